// Round 15
// baseline (3791.177 us; speedup 1.0000x reference)
//
#include <hip/hip_runtime.h>
#include <hip/hip_bf16.h>
#include <math.h>

#define N_C 15000
#define N_D 3000
#define N_G 40000
#define NTOT 58000
#define HID 128
#define HEADS 4
#define DH 32
#define KTOP 8000
#define KROWP 3072
#define NPROBP 46202880u   /* 15040*3072 */
#define EQCAP 1048576u
#define DPB 8

#define SC_DEN 1125899906842624.0   /* 2^50 */
#define SC_AGG 281474976710656.0    /* 2^48 */

static __device__ __forceinline__ unsigned fenc32(float f){
    unsigned u = __float_as_uint(f);
    return (u & 0x80000000u) ? ~u : (u | 0x80000000u);
}
static __device__ __forceinline__ float fdec32(unsigned um){
    return __uint_as_float((um & 0x80000000u) ? (um & 0x7fffffffu) : ~um);
}

// ---- Bit-exact emulation of XLA-CPU / Eigen Cephes f32 exp (pexp) ----
static __device__ __forceinline__ float pexp32f(float x){
    x = fminf(x,  88.3762626647949f);
    x = fmaxf(x, -87.3365478515625f);
    float fx = fmaf(x, 1.44269504088896341f, 0.5f);
    fx = floorf(fx);
    float r = fmaf(fx, -0.693359375f, x);
    r = fmaf(fx, 2.12194440e-4f, r);
    float r2 = __fmul_rn(r, r);
    float y = 1.9875691500E-4f;
    y = fmaf(y, r, 1.3981999507E-3f);
    y = fmaf(y, r, 8.3334519073E-3f);
    y = fmaf(y, r, 4.1665795894E-2f);
    y = fmaf(y, r, 1.6666665459E-1f);
    y = fmaf(y, r, 5.0000001201E-1f);
    y = fmaf(y, r2, r);
    y = __fadd_rn(y, 1.0f);
    int m = (int)fx;
    y = __fmul_rn(y, __uint_as_float((unsigned)(m + 127) << 23));
    return y;
}

// numpy/XLA-style sigmoid: p = fl32( 1 / fl32( 1 + pexp(-x) ) )
static __device__ __forceinline__ float np_sigmoid_f32(float x){
    float e = pexp32f(-x);
    float s = __fadd_rn(1.0f, e);
    return __fdiv_rn(1.0f, s);
}

// ---------- NMAX init to encoded -inf ----------
__global__ void k_init_nmax(unsigned* __restrict__ NMAX){
    int i = blockIdx.x*256 + threadIdx.x;
    if (i < NTOT*HEADS) NMAX[i] = 0x007FFFFFu;
}

// ---------- CSR build: count / scan / fill ----------
__global__ void k_count(const int* __restrict__ edst, unsigned* __restrict__ cnt, int E){
    int i = blockIdx.x*256 + threadIdx.x;
    if (i < E) atomicAdd(&cnt[edst[i]], 1u);
}

__global__ void __launch_bounds__(256) k_scan(const unsigned* __restrict__ cnt,
                                              unsigned* __restrict__ offs, int n){
    __shared__ unsigned ssum[256];
    int tid = threadIdx.x;
    int chunk = (n + 255) / 256;
    int lo = tid*chunk, hi = lo+chunk; if (hi > n) hi = n; if (lo > n) lo = n;
    unsigned s = 0;
    for (int i=lo;i<hi;i++) s += cnt[i];
    ssum[tid] = s; __syncthreads();
    for (int st=1; st<256; st<<=1){
        unsigned t = (tid>=st) ? ssum[tid-st] : 0u;
        __syncthreads();
        ssum[tid] += t;
        __syncthreads();
    }
    unsigned run = ssum[tid] - s;
    for (int i=lo;i<hi;i++){ offs[i] = run; run += cnt[i]; }
    if (tid == 0) offs[n] = ssum[255];
}

__global__ void k_fill(const int* __restrict__ esrc, const int* __restrict__ edst,
                       const unsigned* __restrict__ offs, unsigned* __restrict__ curs,
                       unsigned* __restrict__ csr_src, unsigned* __restrict__ csr_el,
                       int E, int csr_base){
    int i = blockIdx.x*256 + threadIdx.x;
    if (i >= E) return;
    int dst = edst[i];
    unsigned pos = offs[dst] + atomicAdd(&curs[dst], 1u);
    csr_src[csr_base + pos] = (unsigned)esrc[i];
    csr_el [csr_base + pos] = (unsigned)i;
}

// ---------- kqv GEMM: f32 sequential-k FMA; k,q -> KQ (stride 256), v -> V ----------
__global__ void k_kqv(const float* __restrict__ X, const float* __restrict__ W,
                      const float* __restrict__ Bv, float* __restrict__ KQ,
                      float* __restrict__ V, int n0, int ncnt)
{
    __shared__ float sA[16][128];
    int rb = blockIdx.x*16;
    int sec = blockIdx.y;
    int col = threadIdx.x & 127, half = threadIdx.x >> 7;
    for (int i = threadIdx.x; i < 2048; i += 256){
        int r = i >> 7, c = i & 127;
        sA[r][c] = (rb + r < ncnt) ? X[(size_t)(n0+rb+r)*HID + c] : 0.f;
    }
    __syncthreads();
    float acc[8];
#pragma unroll
    for (int i=0;i<8;i++) acc[i]=0.f;
    int wc = sec*128 + col;
    for (int k=0;k<128;k++){
        float w = W[(size_t)k*384 + wc];
#pragma unroll
        for (int i=0;i<8;i++) acc[i] = fmaf(sA[half*8+i][k], w, acc[i]);
    }
    float bb = Bv[wc];
    for (int i=0;i<8;i++){
        int r = rb + half*8 + i;
        if (r >= ncnt) continue;
        float y = __fadd_rn(acc[i], bb);
        if (sec < 2) KQ[(size_t)(n0+r)*256 + sec*128 + col] = y;
        else         V[(size_t)(n0+r)*128 + col] = y;
    }
}

// ---------- per-(row,type) relation transform: OUT[row][128] = fl32(fp64 in[row]·M) ----------
__global__ void __launch_bounds__(256) k_rel(const float* __restrict__ IN, int stride, int secoff,
        const float* __restrict__ Mrel, float* __restrict__ OUT, int n0, int ncnt)
{
    __shared__ float sM[HEADS*DH*DH];
    for (int i=threadIdx.x;i<HEADS*DH*DH;i+=256) sM[i]=Mrel[i];
    __syncthreads();
    int sub = threadIdx.x>>7, lane = threadIdx.x&127;
    int h = lane>>5, f = lane&31;
    int row = blockIdx.x*2 + sub;
    if (row >= ncnt) return;
    float vval = IN[(size_t)(n0+row)*stride + secoff + lane];
    double t = 0.0;
    const float* mh = &sM[h*DH*DH];
#pragma unroll
    for (int d=0; d<DH; ++d)
        t += (double)__shfl(vval, d, 32) * (double)mh[d*DH+f];
    OUT[(size_t)row*HID + lane] = (float)t;
}

// ---------- alpha v5: dst-centric CSR; q loaded once per dst; local head max ----------
__global__ void __launch_bounds__(128) k_alpha_csr(const float* __restrict__ KQ,
        const float* __restrict__ KE,
        const unsigned* __restrict__ csr_src, const unsigned* __restrict__ csr_el,
        const unsigned* __restrict__ offs, const float* __restrict__ Prel,
        float* __restrict__ ALPHA, unsigned* __restrict__ NMAX,
        int eoff, int nodst, int csr_base, int ndst)
{
    int lane = threadIdx.x, h = lane>>5, f = lane&31;
    float p = Prel[h];
    int d0 = blockIdx.x*DPB;
    int d1 = d0+DPB; if (d1 > ndst) d1 = ndst;
    for (int dst=d0; dst<d1; ++dst){
        unsigned beg = offs[dst], end = offs[dst+1];
        if (beg == end) continue;
        float qv = KQ[(size_t)(nodst+dst)*256 + 128 + lane];
        unsigned lmax = 0x007FFFFFu;   // fenc32(-inf)
        for (unsigned j=beg; j<end; ++j){
            unsigned src = csr_src[csr_base+j];
            unsigned el  = csr_el [csr_base+j];
            float ke = KE[(size_t)src*HID + lane];
            double part = (double)qv * (double)ke;
#pragma unroll
            for (int off=16; off>0; off>>=1) part += __shfl_xor(part, off);
            if (f==0){
                float s32 = (float)part;
                float a = __fmul_rn(__fmul_rn(s32, p), 0.17677669529663687f);
                ALPHA[(size_t)(eoff+el)*HEADS + h] = a;
                unsigned enc = fenc32(a);
                if (enc > lmax) lmax = enc;
            }
        }
        if (f==0) atomicMax(&NMAX[(size_t)(nodst+dst)*HEADS + h], lmax);
    }
}

// ---------- ex = pexp(f32(a-m)); fixed-point 2^50 deterministic den sum ----------
__global__ void k_expsum(const float* __restrict__ ALPHA,
                         const int* __restrict__ edst, const unsigned* __restrict__ NMAX,
                         unsigned long long* __restrict__ NSUM,
                         int E, int eoff, int nodst)
{
    int i = blockIdx.x*256 + threadIdx.x;
    if (i >= E*HEADS) return;
    int e = i>>2, h = i&3;
    int dst = edst[e];
    float m = fdec32(NMAX[(size_t)(nodst+dst)*HEADS + h]);
    float a = ALPHA[(size_t)(eoff+e)*HEADS + h];
    float ex = pexp32f(__fsub_rn(a, m));
    atomicAdd(&NSUM[(size_t)(nodst+dst)*HEADS + h],
              (unsigned long long)(long long)llrint((double)ex * SC_DEN));
}

// ---------- w precompute (den folded in): ALPHA <- fl32(pexp(fl32(a-m))/denp) ----------
__global__ void k_wgt(float* __restrict__ ALPHA, const int* __restrict__ edst,
                      const unsigned* __restrict__ NMAX,
                      const unsigned long long* __restrict__ NSUM,
                      int E, int eoff, int nodst)
{
    int i = blockIdx.x*256 + threadIdx.x;
    if (i >= E*HEADS) return;
    int e = i>>2, h = i&3;
    int dst = edst[e];
    float m = fdec32(NMAX[(size_t)(nodst+dst)*HEADS + h]);
    float a = ALPHA[(size_t)(eoff+e)*HEADS + h];
    float ex = pexp32f(__fsub_rn(a, m));
    float den = (float)((double)(long long)NSUM[(size_t)(nodst+dst)*HEADS + h] * (1.0/SC_DEN));
    float denp = __fadd_rn(den, 1e-16f);
    ALPHA[(size_t)(eoff+e)*HEADS + h] = __fdiv_rn(ex, denp);
}

// ---------- aggregation: CSR gather of precomputed w,ve; no barriers ----------
__global__ void __launch_bounds__(128) k_agg2(
    const float* __restrict__ VE, const unsigned* __restrict__ csr_src,
    const unsigned* __restrict__ csr_el, const unsigned* __restrict__ offs,
    const float* __restrict__ W, unsigned long long* __restrict__ AGG,
    int eoff, int nodst, int csr_base, int ndst)
{
    int lane = threadIdx.x, h = lane>>5;
    int d0 = blockIdx.x*DPB;
    int d1 = d0+DPB; if (d1 > ndst) d1 = ndst;
    for (int dst=d0; dst<d1; ++dst){
        unsigned beg = offs[dst], end = offs[dst+1];
        if (beg == end) continue;
        long long acc = 0;
        for (unsigned j=beg; j<end; ++j){
            unsigned src = csr_src[csr_base+j];
            unsigned el  = csr_el [csr_base+j];
            float w  = W[(size_t)(eoff+el)*HEADS + h];
            float ve = VE[(size_t)src*HID + lane];
            float prod = __fmul_rn(w, ve);
            acc += llrint((double)prod*SC_AGG);
        }
        size_t o = (size_t)(nodst+dst)*HID + lane;
        AGG[o] = AGG[o] + (unsigned long long)acc;
    }
}

// ---------- out: X = a_s*(gelu(agg)@W + b) + (1-a_s)*X (in place) ----------
__global__ void k_outl(const unsigned long long* __restrict__ AGG,
                       const float* __restrict__ W, const float* __restrict__ Bv,
                       float* __restrict__ X,
                       const float* __restrict__ skipv, int n0, int ncnt)
{
    __shared__ float sA[16][128];
    int rb = blockIdx.x*16;
    int col = threadIdx.x&127, half = threadIdx.x>>7;
    for (int i=threadIdx.x;i<2048;i+=256){
        int r=i>>7,c=i&127;
        float g = 0.f;
        if (rb+r<ncnt){
            float x = (float)((double)(long long)AGG[(size_t)(n0+rb+r)*128 + c] * (1.0/SC_AGG));
            float t = __fdiv_rn(x, 1.4142135623730951f);
            float ef = (float)erf((double)t);
            g = __fmul_rn(__fmul_rn(0.5f, x), __fadd_rn(1.0f, ef));
        }
        sA[r][c]=g;
    }
    __syncthreads();
    float acc[8];
#pragma unroll
    for(int i=0;i<8;i++)acc[i]=0.f;
    for(int k=0;k<128;k++){
        float w=W[(size_t)k*128+col];
#pragma unroll
        for(int i=0;i<8;i++)acc[i]=fmaf(sA[half*8+i][k], w, acc[i]);
    }
    float a_s = np_sigmoid_f32(skipv[0]);
    float om  = __fsub_rn(1.0f, a_s);
    for(int i=0;i<8;i++){
        int r=rb+half*8+i;
        if(r<ncnt){
            size_t idx=(size_t)(n0+r)*128+col;
            float o = __fadd_rn(acc[i], Bv[col]);
            X[idx] = __fadd_rn(__fmul_rn(a_s, o), __fmul_rn(om, X[idx]));
        }
    }
}

// ---------- final z GEMM: f32 sequential-k FMA ----------
__global__ void k_zfin(const float* __restrict__ X, const float* __restrict__ W,
                       const float* __restrict__ Bv, float* __restrict__ Z,
                       int n0, int ncnt, int zoff)
{
    __shared__ float sA[16][128];
    int rb=blockIdx.x*16;
    int col=threadIdx.x&63, quad=threadIdx.x>>6;
    for(int i=threadIdx.x;i<2048;i+=256){
        int r=i>>7,c=i&127;
        sA[r][c]=(rb+r<ncnt)?X[(size_t)(n0+rb+r)*128+c]:0.f;
    }
    __syncthreads();
    float acc[4]={0.f,0.f,0.f,0.f};
    for(int k=0;k<128;k++){
        float w=W[(size_t)k*64+col];
#pragma unroll
        for(int i=0;i<4;i++)acc[i]=fmaf(sA[quad*4+i][k], w, acc[i]);
    }
    for(int i=0;i<4;i++){
        int r=rb+quad*4+i;
        if(r<ncnt)Z[(size_t)(zoff+r)*64+col]=__fadd_rn(acc[i], Bv[col]);
    }
}

// ---------- train edge mask (padded index space) ----------
__global__ void k_mask(const int* __restrict__ tr, unsigned* __restrict__ MASK, int E){
    int i = blockIdx.x*256 + threadIdx.x;
    if (i>=E) return;
    unsigned bit = (unsigned)(tr[i]*KROWP + tr[E+i]);
    atomicOr(&MASK[bit>>5], 1u<<(bit&31));
}

// ---------- keys: 64x64 tile, uint4 aligned stores, fused level-0 hist ----------
__global__ void __launch_bounds__(256) k_keys(const float* __restrict__ Z,
        const unsigned* __restrict__ MASK, unsigned* __restrict__ KEYS,
        unsigned* __restrict__ STATE)
{
    __shared__ float sC[64][65];
    __shared__ float sD[64][65];
    __shared__ unsigned shh[256];
    int db = blockIdx.x*64, cb = blockIdx.y*64;
    shh[threadIdx.x] = 0u;
    for (int i=threadIdx.x;i<4096;i+=256){
        int r=i>>6, c=i&63;
        sC[r][c] = (cb+r<N_C) ? Z[(size_t)(cb+r)*64+c] : 0.f;
        sD[r][c] = (db+r<N_D) ? Z[(size_t)(N_C+db+r)*64+c] : 0.f;
    }
    __syncthreads();
    int tx = threadIdx.x & 15, ty = threadIdx.x >> 4;
    int r0 = ty*4, c0 = tx*4;
    float acc[4][4];
#pragma unroll
    for(int i=0;i<4;i++)
#pragma unroll
        for(int j=0;j<4;j++) acc[i][j]=0.f;
    for (int k=0;k<64;k++){
        float a0=sC[r0][k],a1=sC[r0+1][k],a2=sC[r0+2][k],a3=sC[r0+3][k];
        float b0=sD[c0][k],b1=sD[c0+1][k],b2=sD[c0+2][k],b3=sD[c0+3][k];
        acc[0][0]=fmaf(a0,b0,acc[0][0]); acc[0][1]=fmaf(a0,b1,acc[0][1]);
        acc[0][2]=fmaf(a0,b2,acc[0][2]); acc[0][3]=fmaf(a0,b3,acc[0][3]);
        acc[1][0]=fmaf(a1,b0,acc[1][0]); acc[1][1]=fmaf(a1,b1,acc[1][1]);
        acc[1][2]=fmaf(a1,b2,acc[1][2]); acc[1][3]=fmaf(a1,b3,acc[1][3]);
        acc[2][0]=fmaf(a2,b0,acc[2][0]); acc[2][1]=fmaf(a2,b1,acc[2][1]);
        acc[2][2]=fmaf(a2,b2,acc[2][2]); acc[2][3]=fmaf(a2,b3,acc[2][3]);
        acc[3][0]=fmaf(a3,b0,acc[3][0]); acc[3][1]=fmaf(a3,b1,acc[3][1]);
        acc[3][2]=fmaf(a3,b2,acc[3][2]); acc[3][3]=fmaf(a3,b3,acc[3][3]);
    }
    unsigned lastb=0xFFFFFFFFu, rcnt=0;
#pragma unroll
    for (int i=0;i<4;i++){
        int cr = cb + r0 + i;
        int dcb = db + c0;
        bool rok = (cr < N_C);
        unsigned mword = rok ? MASK[((size_t)cr*KROWP + dcb)>>5] : 0u;
        unsigned kk[4];
#pragma unroll
        for (int j=0;j<4;j++){
            int dc = dcb + j;
            unsigned key = 0u;
            if (rok && dc < N_D){
                float p = np_sigmoid_f32(acc[i][j]);
                key = fenc32(p);
                if (mword & (1u << (dc & 31))) key = 0u;
            }
            kk[j] = key;
            unsigned b = key >> 24;
            if (b == lastb) rcnt++;
            else { if (rcnt) atomicAdd(&shh[lastb], rcnt); lastb = b; rcnt = 1; }
        }
        *reinterpret_cast<uint4*>(&KEYS[(size_t)cr*KROWP + dcb]) =
            make_uint4(kk[0],kk[1],kk[2],kk[3]);
    }
    if (rcnt) atomicAdd(&shh[lastb], rcnt);
    __syncthreads();
    unsigned v = shh[threadIdx.x];
    if (v) atomicAdd(&STATE[8+threadIdx.x], v);
}

// ---------- radix select levels 1..3 (RLE bucket aggregation) ----------
__global__ void k_hist(const unsigned* __restrict__ KEYS, unsigned* __restrict__ STATE, int level){
    __shared__ unsigned sh[256];
    for (int i=threadIdx.x;i<256;i+=blockDim.x) sh[i]=0;
    __syncthreads();
    unsigned prefix = STATE[0];
    int shift = 24 - 8*level;
    size_t stride = (size_t)gridDim.x*blockDim.x;
    unsigned lastb = 0xFFFFFFFFu, rcnt = 0;
    for (size_t i = (size_t)blockIdx.x*blockDim.x+threadIdx.x; i < (size_t)NPROBP; i += stride){
        unsigned k = KEYS[i];
        if ((k >> (shift+8)) != prefix) continue;
        unsigned b = (k>>shift)&255u;
        if (b == lastb) rcnt++;
        else { if (rcnt) atomicAdd(&sh[lastb], rcnt); lastb = b; rcnt = 1; }
    }
    if (rcnt) atomicAdd(&sh[lastb], rcnt);
    __syncthreads();
    for (int i=threadIdx.x;i<256;i+=blockDim.x) if (sh[i]) atomicAdd(&STATE[8+i], sh[i]);
}

__global__ void k_hfin(unsigned* STATE){
    if (threadIdx.x==0 && blockIdx.x==0){
        unsigned cnt = STATE[1];
        unsigned prefix = STATE[0];
        int b = 255;
        for (; b>0; --b){
            unsigned c = STATE[8+b];
            if (cnt + c >= (unsigned)KTOP) break;
            cnt += c;
        }
        STATE[0] = (prefix<<8) | (unsigned)b;
        STATE[1] = cnt;
        for (int i=0;i<256;i++) STATE[8+i]=0;
    }
}

// ---------- collect: store (key<<32)|~idx composites for the greater set ----------
__global__ void k_collect(const unsigned* __restrict__ KEYS, unsigned* __restrict__ STATE,
                          unsigned long long* __restrict__ CANDI, unsigned* __restrict__ EQI)
{
    unsigned T = STATE[0];
    size_t stride = (size_t)gridDim.x*blockDim.x;
    for (size_t i=(size_t)blockIdx.x*blockDim.x+threadIdx.x; i<(size_t)NPROBP; i+=stride){
        unsigned k = KEYS[i];
        if (k > T){
            unsigned pos = atomicAdd(&STATE[2], 1u);
            if (pos < 8192u)
                CANDI[pos] = ((unsigned long long)k << 32)
                           | (unsigned long long)(0xFFFFFFFFu - (unsigned)i);
        } else if (k == T){
            unsigned pos = atomicAdd(&STATE[3], 1u);
            if (pos < EQCAP) EQI[pos] = (unsigned)i;
        }
    }
}

// ---------- rank-scatter exact order: multi-block, output-identical to sort ----------
__global__ void __launch_bounds__(256) k_rank(const unsigned long long* __restrict__ CANDI,
        const unsigned* __restrict__ STATE, const unsigned* __restrict__ EQI,
        float* __restrict__ OUT)
{
    __shared__ unsigned long long sc[2048];
    unsigned* se = (unsigned*)sc;
    unsigned G = STATE[2]; if (G > 8192u) G = 8192u;   // radix guarantees G < KTOP
    unsigned nE = STATE[3]; if (nE > 8192u) nE = 8192u;
    unsigned T = STATE[0];
    unsigned need = ((unsigned)KTOP > G) ? ((unsigned)KTOP - G) : 0u;

    int phase = blockIdx.x & 1;
    unsigned i = (blockIdx.x >> 1)*256 + threadIdx.x;   // 0..8191
    if (phase == 0){
        unsigned long long ci = (i < G) ? CANDI[i] : 0ull;
        unsigned rank = 0;
        for (unsigned t0=0; t0<G; t0+=2048u){
            unsigned tl = G - t0; if (tl > 2048u) tl = 2048u;
            __syncthreads();
            for (unsigned k=threadIdx.x; k<tl; k+=256u) sc[k] = CANDI[t0+k];
            __syncthreads();
            if (i < G)
                for (unsigned k=0; k<tl; ++k) rank += (sc[k] > ci) ? 1u : 0u;
        }
        if (i < G){
            unsigned idx = 0xFFFFFFFFu - (unsigned)(ci & 0xFFFFFFFFull);
            unsigned key = (unsigned)(ci >> 32);
            unsigned c = idx/KROWP, d = idx - c*KROWP;
            OUT[rank] = (float)c; OUT[KTOP+rank] = (float)d; OUT[2*KTOP+rank] = fdec32(key);
        }
    } else {
        float pT = fdec32(T);
        unsigned ii = (i < nE) ? EQI[i] : 0xFFFFFFFFu;
        unsigned rank = 0;
        for (unsigned t0=0; t0<nE; t0+=2048u){
            unsigned tl = nE - t0; if (tl > 2048u) tl = 2048u;
            __syncthreads();
            for (unsigned k=threadIdx.x; k<tl; k+=256u) se[k] = EQI[t0+k];
            __syncthreads();
            if (i < nE)
                for (unsigned k=0; k<tl; ++k) rank += (se[k] < ii) ? 1u : 0u;
        }
        if (i < nE && rank < need){
            unsigned c = ii/KROWP, d = ii - c*KROWP;
            unsigned rr = G + rank;
            OUT[rr] = (float)c; OUT[KTOP+rr] = (float)d; OUT[2*KTOP+rr] = pT;
        }
    }
}

// ------------------------------------------------------------------
extern "C" void kernel_launch(void* const* d_in, const int* in_sizes, int n_in,
                              void* d_out, int out_size, void* d_ws, size_t ws_size,
                              hipStream_t stream)
{
    const float* embC = (const float*)d_in[0];
    const float* embD = (const float*)d_in[1];
    const float* embG = (const float*)d_in[2];
    const float* Wkqv = (const float*)d_in[3];
    const float* bkqv = (const float*)d_in[4];
    const float* Wout = (const float*)d_in[5];
    const float* bout = (const float*)d_in[6];
    const float* skipv= (const float*)d_in[7];
    const float* arel = (const float*)d_in[8];
    const float* mrel = (const float*)d_in[9];
    const float* prel = (const float*)d_in[10];
    const float* Wfin = (const float*)d_in[11];
    const float* bfin = (const float*)d_in[12];
    const int* ei[5] = {(const int*)d_in[13],(const int*)d_in[14],(const int*)d_in[15],
                        (const int*)d_in[16],(const int*)d_in[17]};
    const int* tri  = (const int*)d_in[18];
    int trE = in_sizes[18]/2;

    static const int NODE_OFF[3] = {0, N_C, N_C + N_D};
    static const int NODE_CNT[3] = {N_C, N_D, N_G};
    static const int EM_ST[5] = {0,1,0,2,2};
    static const int EM_DT[5] = {1,0,2,0,2};
    static const int EM_E[5]  = {80000,80000,250000,250000,400000};
    static const int EM_OFF[5]= {0,80000,160000,410000,660000};
    static const int DOFF[5] = {0,3000,18000,58000,73000};
    static const int OFO[5]  = {0,3001,18002,58003,73004};

    // ---- workspace layout; PEAK = 249,192,032 bytes ----
    char* ws = (char*)d_ws;
    float* X  = (float*)(ws + 0);                        // 29,696,000
    float* KQ = (float*)(ws + 29696000);                 // 59,392,000
    float* V  = (float*)(ws + 89088000);                 // 29,696,000
    float* ALPHA = (float*)(ws + 118784000);             // 16,960,000 (becomes W)
    unsigned* NMAX = (unsigned*)(ws + 135744000);        // 928,000
    unsigned long long* NSUM = (unsigned long long*)(ws + 136672000); // 1,856,000
    unsigned long long* AGG = (unsigned long long*)(ws + 139456000);  // 59,392,000
    float* VE = (float*)(ws + 198848000);                // 20,480,000
    unsigned* OFFS = (unsigned*)(ws + 219328000);        // 452,032
    unsigned* CURS = (unsigned*)(ws + 219780032);        // 452,000
    unsigned* CSRS = (unsigned*)(ws + 220232032);        // 4,240,000
    unsigned* CSRE = (unsigned*)(ws + 224472032);        // 4,240,000 .. 228,712,032
    float* KE = (float*)(ws + 228712032);                // 20,480,000 .. 249,192,032
    // decode-phase overlays (tenants dead by first use):
    unsigned* KEYS = (unsigned*)(ws + 0);                // 184,811,520
    float* Z = (float*)(ws + 198848000);                 // 4,608,000 (ex-VE)
    unsigned* MASK = (unsigned*)(ws + 203456000);        // 5,760,000
    unsigned* STATE= (unsigned*)(ws + 209216000);        // 8,192
    unsigned long long* CANDI = (unsigned long long*)(ws + 209224192); // 65,536
    unsigned* EQI  = (unsigned*)(ws + 209289728);        // 4,194,304 .. 213,484,032

    hipMemcpyAsync(X,                          embC, (size_t)N_C*HID*4, hipMemcpyDeviceToDevice, stream);
    hipMemcpyAsync(X + (size_t)N_C*HID,        embD, (size_t)N_D*HID*4, hipMemcpyDeviceToDevice, stream);
    hipMemcpyAsync(X + (size_t)(N_C+N_D)*HID,  embG, (size_t)N_G*HID*4, hipMemcpyDeviceToDevice, stream);

    // ---- build CSR once; reused by both layers ----
    hipMemsetAsync(CURS, 0, 113000*4, stream);
    for (int e=0;e<5;e++)
        k_count<<<(EM_E[e]+255)/256, 256, 0, stream>>>(ei[e]+EM_E[e], CURS + DOFF[e], EM_E[e]);
    for (int e=0;e<5;e++)
        k_scan<<<1, 256, 0, stream>>>(CURS + DOFF[e], OFFS + OFO[e], NODE_CNT[EM_DT[e]]);
    hipMemsetAsync(CURS, 0, 113000*4, stream);
    for (int e=0;e<5;e++)
        k_fill<<<(EM_E[e]+255)/256, 256, 0, stream>>>(ei[e], ei[e]+EM_E[e],
            OFFS + OFO[e], CURS + DOFF[e], CSRS, CSRE, EM_E[e], EM_OFF[e]);

    for (int l=0; l<2; ++l){
        k_init_nmax<<<(NTOT*HEADS+255)/256, 256, 0, stream>>>(NMAX);
        hipMemsetAsync(NSUM, 0, (size_t)NTOT*HEADS*8, stream);
        hipMemsetAsync(AGG,  0, (size_t)NTOT*HID*8,  stream);
        for (int t=0;t<3;t++){
            k_kqv<<<dim3((NODE_CNT[t]+15)/16, 3), 256, 0, stream>>>(
                X, Wkqv + (size_t)(l*3+t)*128*384, bkqv + (size_t)(l*3+t)*384,
                KQ, V, NODE_OFF[t], NODE_CNT[t]);
        }
        for (int e=0;e<5;e++){
            int nsrc = NODE_CNT[EM_ST[e]];
            int ndst = NODE_CNT[EM_DT[e]];
            k_rel<<<(nsrc+1)/2, 256, 0, stream>>>(
                KQ, 256, 0, arel + (size_t)(l*5+e)*HEADS*DH*DH, KE,
                NODE_OFF[EM_ST[e]], nsrc);
            k_alpha_csr<<<(ndst+DPB-1)/DPB, 128, 0, stream>>>(
                KQ, KE, CSRS, CSRE, OFFS + OFO[e],
                prel + (size_t)(l*5+e)*HEADS,
                ALPHA, NMAX, EM_OFF[e], NODE_OFF[EM_DT[e]], EM_OFF[e], ndst);
        }
        for (int e=0;e<5;e++){
            int tot = EM_E[e]*HEADS;
            k_expsum<<<(tot+255)/256, 256, 0, stream>>>(
                ALPHA, ei[e]+EM_E[e], NMAX, NSUM, EM_E[e], EM_OFF[e], NODE_OFF[EM_DT[e]]);
        }
        for (int e=0;e<5;e++){
            int tot = EM_E[e]*HEADS;
            k_wgt<<<(tot+255)/256, 256, 0, stream>>>(
                ALPHA, ei[e]+EM_E[e], NMAX, NSUM, EM_E[e], EM_OFF[e], NODE_OFF[EM_DT[e]]);
        }
        for (int e=0;e<5;e++){
            int nsrc = NODE_CNT[EM_ST[e]];
            int ndst = NODE_CNT[EM_DT[e]];
            k_rel<<<(nsrc+1)/2, 256, 0, stream>>>(
                V, 128, 0, mrel + (size_t)(l*5+e)*HEADS*DH*DH, VE,
                NODE_OFF[EM_ST[e]], nsrc);
            k_agg2<<<(ndst+DPB-1)/DPB, 128, 0, stream>>>(
                VE, CSRS, CSRE, OFFS + OFO[e], ALPHA, AGG,
                EM_OFF[e], NODE_OFF[EM_DT[e]], EM_OFF[e], ndst);
        }
        for (int t=0;t<3;t++){
            k_outl<<<(NODE_CNT[t]+15)/16, 256, 0, stream>>>(
                AGG, Wout + (size_t)(l*3+t)*128*128, bout + (size_t)(l*3+t)*128,
                X, skipv + (l*3+t), NODE_OFF[t], NODE_CNT[t]);
        }
    }

    k_zfin<<<(N_C+15)/16, 256, 0, stream>>>(X, Wfin + 0,      bfin + 0,  Z, 0,   N_C, 0);
    k_zfin<<<(N_D+15)/16, 256, 0, stream>>>(X, Wfin + 128*64, bfin + 64, Z, N_C, N_D, N_C);

    hipMemsetAsync(MASK, 0, 5760000, stream);
    hipMemsetAsync(STATE, 0, 8192, stream);
    k_mask<<<(trE+255)/256, 256, 0, stream>>>(tri, MASK, trE);
    k_keys<<<dim3(48, 235), 256, 0, stream>>>(Z, MASK, KEYS, STATE);
    k_hfin<<<1, 64, 0, stream>>>(STATE);
    for (int lev=1; lev<4; ++lev){
        k_hist<<<2048, 256, 0, stream>>>(KEYS, STATE, lev);
        k_hfin<<<1, 64, 0, stream>>>(STATE);
    }
    k_collect<<<2048, 256, 0, stream>>>(KEYS, STATE, CANDI, EQI);
    k_rank<<<64, 256, 0, stream>>>(CANDI, STATE, EQI, (float*)d_out);
}

// Round 16
// 3444.937 us; speedup vs baseline: 1.1005x; 1.1005x over previous
//
#include <hip/hip_runtime.h>
#include <hip/hip_bf16.h>
#include <math.h>

#define N_C 15000
#define N_D 3000
#define N_G 40000
#define NTOT 58000
#define HID 128
#define HEADS 4
#define DH 32
#define KTOP 8000
#define KROWP 3072
#define NPROBP 46202880u   /* 15040*3072 */
#define EQCAP 1048576u
#define DPB 8
#define EPB 8              /* edges per 128-lane group in k_alpha4 */

#define SC_DEN 1125899906842624.0   /* 2^50 */
#define SC_AGG 281474976710656.0    /* 2^48 */

static __device__ __forceinline__ unsigned fenc32(float f){
    unsigned u = __float_as_uint(f);
    return (u & 0x80000000u) ? ~u : (u | 0x80000000u);
}
static __device__ __forceinline__ float fdec32(unsigned um){
    return __uint_as_float((um & 0x80000000u) ? (um & 0x7fffffffu) : ~um);
}

// ---- Bit-exact emulation of XLA-CPU / Eigen Cephes f32 exp (pexp) ----
static __device__ __forceinline__ float pexp32f(float x){
    x = fminf(x,  88.3762626647949f);
    x = fmaxf(x, -87.3365478515625f);
    float fx = fmaf(x, 1.44269504088896341f, 0.5f);
    fx = floorf(fx);
    float r = fmaf(fx, -0.693359375f, x);
    r = fmaf(fx, 2.12194440e-4f, r);
    float r2 = __fmul_rn(r, r);
    float y = 1.9875691500E-4f;
    y = fmaf(y, r, 1.3981999507E-3f);
    y = fmaf(y, r, 8.3334519073E-3f);
    y = fmaf(y, r, 4.1665795894E-2f);
    y = fmaf(y, r, 1.6666665459E-1f);
    y = fmaf(y, r, 5.0000001201E-1f);
    y = fmaf(y, r2, r);
    y = __fadd_rn(y, 1.0f);
    int m = (int)fx;
    y = __fmul_rn(y, __uint_as_float((unsigned)(m + 127) << 23));
    return y;
}

// numpy/XLA-style sigmoid: p = fl32( 1 / fl32( 1 + pexp(-x) ) )
static __device__ __forceinline__ float np_sigmoid_f32(float x){
    float e = pexp32f(-x);
    float s = __fadd_rn(1.0f, e);
    return __fdiv_rn(1.0f, s);
}

// ---------- NMAX init to encoded -inf ----------
__global__ void k_init_nmax(unsigned* __restrict__ NMAX){
    int i = blockIdx.x*256 + threadIdx.x;
    if (i < NTOT*HEADS) NMAX[i] = 0x007FFFFFu;
}

// ---------- CSR build: count / scan / fill ----------
__global__ void k_count(const int* __restrict__ edst, unsigned* __restrict__ cnt, int E){
    int i = blockIdx.x*256 + threadIdx.x;
    if (i < E) atomicAdd(&cnt[edst[i]], 1u);
}

__global__ void __launch_bounds__(256) k_scan(const unsigned* __restrict__ cnt,
                                              unsigned* __restrict__ offs, int n){
    __shared__ unsigned ssum[256];
    int tid = threadIdx.x;
    int chunk = (n + 255) / 256;
    int lo = tid*chunk, hi = lo+chunk; if (hi > n) hi = n; if (lo > n) lo = n;
    unsigned s = 0;
    for (int i=lo;i<hi;i++) s += cnt[i];
    ssum[tid] = s; __syncthreads();
    for (int st=1; st<256; st<<=1){
        unsigned t = (tid>=st) ? ssum[tid-st] : 0u;
        __syncthreads();
        ssum[tid] += t;
        __syncthreads();
    }
    unsigned run = ssum[tid] - s;
    for (int i=lo;i<hi;i++){ offs[i] = run; run += cnt[i]; }
    if (tid == 0) offs[n] = ssum[255];
}

__global__ void k_fill(const int* __restrict__ esrc, const int* __restrict__ edst,
                       const unsigned* __restrict__ offs, unsigned* __restrict__ curs,
                       unsigned* __restrict__ csr_src, unsigned* __restrict__ csr_el,
                       int E, int csr_base){
    int i = blockIdx.x*256 + threadIdx.x;
    if (i >= E) return;
    int dst = edst[i];
    unsigned pos = offs[dst] + atomicAdd(&curs[dst], 1u);
    csr_src[csr_base + pos] = (unsigned)esrc[i];
    csr_el [csr_base + pos] = (unsigned)i;
}

// ---------- kqv GEMM: f32 sequential-k FMA; k,q -> KQ (stride 256), v -> V ----------
__global__ void k_kqv(const float* __restrict__ X, const float* __restrict__ W,
                      const float* __restrict__ Bv, float* __restrict__ KQ,
                      float* __restrict__ V, int n0, int ncnt)
{
    __shared__ float sA[16][128];
    int rb = blockIdx.x*16;
    int sec = blockIdx.y;
    int col = threadIdx.x & 127, half = threadIdx.x >> 7;
    for (int i = threadIdx.x; i < 2048; i += 256){
        int r = i >> 7, c = i & 127;
        sA[r][c] = (rb + r < ncnt) ? X[(size_t)(n0+rb+r)*HID + c] : 0.f;
    }
    __syncthreads();
    float acc[8];
#pragma unroll
    for (int i=0;i<8;i++) acc[i]=0.f;
    int wc = sec*128 + col;
    for (int k=0;k<128;k++){
        float w = W[(size_t)k*384 + wc];
#pragma unroll
        for (int i=0;i<8;i++) acc[i] = fmaf(sA[half*8+i][k], w, acc[i]);
    }
    float bb = Bv[wc];
    for (int i=0;i<8;i++){
        int r = rb + half*8 + i;
        if (r >= ncnt) continue;
        float y = __fadd_rn(acc[i], bb);
        if (sec < 2) KQ[(size_t)(n0+r)*256 + sec*128 + col] = y;
        else         V[(size_t)(n0+r)*128 + col] = y;
    }
}

// ---------- per-(row,type) relation transform: OUT[row][128] = fl32(fp64 in[row]·M) ----------
__global__ void __launch_bounds__(256) k_rel(const float* __restrict__ IN, int stride, int secoff,
        const float* __restrict__ Mrel, float* __restrict__ OUT, int n0, int ncnt)
{
    __shared__ float sM[HEADS*DH*DH];
    for (int i=threadIdx.x;i<HEADS*DH*DH;i+=256) sM[i]=Mrel[i];
    __syncthreads();
    int sub = threadIdx.x>>7, lane = threadIdx.x&127;
    int h = lane>>5, f = lane&31;
    int row = blockIdx.x*2 + sub;
    if (row >= ncnt) return;
    float vval = IN[(size_t)(n0+row)*stride + secoff + lane];
    double t = 0.0;
    const float* mh = &sM[h*DH*DH];
#pragma unroll
    for (int d=0; d<DH; ++d)
        t += (double)__shfl(vval, d, 32) * (double)mh[d*DH+f];
    OUT[(size_t)row*HID + lane] = (float)t;
}

// ---------- alpha v4 (R14 verified): per-edge dot of q[dst] and KE[src]; edge-parallel ----------
__global__ void __launch_bounds__(256) k_alpha4(const float* __restrict__ KQ,
        const float* __restrict__ KE,
        const int* __restrict__ esrc, const int* __restrict__ edst,
        const float* __restrict__ Prel,
        float* __restrict__ ALPHA, unsigned* __restrict__ NMAX,
        int E, int eoff, int nodst)
{
    int sub = threadIdx.x>>7, lane = threadIdx.x&127;
    int h = lane>>5, f = lane&31;
    float p = Prel[h];
    int ebase = (blockIdx.x*2 + sub) * EPB;
#pragma unroll
    for (int i=0;i<EPB;i++){
        int e = ebase + i;
        if (e >= E) return;
        int src = esrc[e], dst = edst[e];
        float ke = KE[(size_t)src*HID + lane];
        float qv = KQ[(size_t)(nodst+dst)*256 + 128 + lane];
        double part = (double)qv * (double)ke;
#pragma unroll
        for (int off=16; off>0; off>>=1) part += __shfl_xor(part, off);
        if (f==0){
            float s32 = (float)part;
            float a = __fmul_rn(__fmul_rn(s32, p), 0.17677669529663687f);
            ALPHA[(size_t)(eoff+e)*HEADS + h] = a;
            atomicMax(&NMAX[(size_t)(nodst+dst)*HEADS + h], fenc32(a));
        }
    }
}

// ---------- ex = pexp(f32(a-m)); fixed-point 2^50 deterministic den sum ----------
__global__ void k_expsum(const float* __restrict__ ALPHA,
                         const int* __restrict__ edst, const unsigned* __restrict__ NMAX,
                         unsigned long long* __restrict__ NSUM,
                         int E, int eoff, int nodst)
{
    int i = blockIdx.x*256 + threadIdx.x;
    if (i >= E*HEADS) return;
    int e = i>>2, h = i&3;
    int dst = edst[e];
    float m = fdec32(NMAX[(size_t)(nodst+dst)*HEADS + h]);
    float a = ALPHA[(size_t)(eoff+e)*HEADS + h];
    float ex = pexp32f(__fsub_rn(a, m));
    atomicAdd(&NSUM[(size_t)(nodst+dst)*HEADS + h],
              (unsigned long long)(long long)llrint((double)ex * SC_DEN));
}

// ---------- w precompute (den folded in): ALPHA <- fl32(pexp(fl32(a-m))/denp) ----------
__global__ void k_wgt(float* __restrict__ ALPHA, const int* __restrict__ edst,
                      const unsigned* __restrict__ NMAX,
                      const unsigned long long* __restrict__ NSUM,
                      int E, int eoff, int nodst)
{
    int i = blockIdx.x*256 + threadIdx.x;
    if (i >= E*HEADS) return;
    int e = i>>2, h = i&3;
    int dst = edst[e];
    float m = fdec32(NMAX[(size_t)(nodst+dst)*HEADS + h]);
    float a = ALPHA[(size_t)(eoff+e)*HEADS + h];
    float ex = pexp32f(__fsub_rn(a, m));
    float den = (float)((double)(long long)NSUM[(size_t)(nodst+dst)*HEADS + h] * (1.0/SC_DEN));
    float denp = __fadd_rn(den, 1e-16f);
    ALPHA[(size_t)(eoff+e)*HEADS + h] = __fdiv_rn(ex, denp);
}

// ---------- aggregation: CSR gather of precomputed w,ve; no barriers ----------
__global__ void __launch_bounds__(128) k_agg2(
    const float* __restrict__ VE, const unsigned* __restrict__ csr_src,
    const unsigned* __restrict__ csr_el, const unsigned* __restrict__ offs,
    const float* __restrict__ W, unsigned long long* __restrict__ AGG,
    int eoff, int nodst, int csr_base, int ndst)
{
    int lane = threadIdx.x, h = lane>>5;
    int d0 = blockIdx.x*DPB;
    int d1 = d0+DPB; if (d1 > ndst) d1 = ndst;
    for (int dst=d0; dst<d1; ++dst){
        unsigned beg = offs[dst], end = offs[dst+1];
        if (beg == end) continue;
        long long acc = 0;
        for (unsigned j=beg; j<end; ++j){
            unsigned src = csr_src[csr_base+j];
            unsigned el  = csr_el [csr_base+j];
            float w  = W[(size_t)(eoff+el)*HEADS + h];
            float ve = VE[(size_t)src*HID + lane];
            float prod = __fmul_rn(w, ve);
            acc += llrint((double)prod*SC_AGG);
        }
        size_t o = (size_t)(nodst+dst)*HID + lane;
        AGG[o] = AGG[o] + (unsigned long long)acc;
    }
}

// ---------- out: X = a_s*(gelu(agg)@W + b) + (1-a_s)*X (in place) ----------
__global__ void k_outl(const unsigned long long* __restrict__ AGG,
                       const float* __restrict__ W, const float* __restrict__ Bv,
                       float* __restrict__ X,
                       const float* __restrict__ skipv, int n0, int ncnt)
{
    __shared__ float sA[16][128];
    int rb = blockIdx.x*16;
    int col = threadIdx.x&127, half = threadIdx.x>>7;
    for (int i=threadIdx.x;i<2048;i+=256){
        int r=i>>7,c=i&127;
        float g = 0.f;
        if (rb+r<ncnt){
            float x = (float)((double)(long long)AGG[(size_t)(n0+rb+r)*128 + c] * (1.0/SC_AGG));
            float t = __fdiv_rn(x, 1.4142135623730951f);
            float ef = (float)erf((double)t);
            g = __fmul_rn(__fmul_rn(0.5f, x), __fadd_rn(1.0f, ef));
        }
        sA[r][c]=g;
    }
    __syncthreads();
    float acc[8];
#pragma unroll
    for(int i=0;i<8;i++)acc[i]=0.f;
    for(int k=0;k<128;k++){
        float w=W[(size_t)k*128+col];
#pragma unroll
        for(int i=0;i<8;i++)acc[i]=fmaf(sA[half*8+i][k], w, acc[i]);
    }
    float a_s = np_sigmoid_f32(skipv[0]);
    float om  = __fsub_rn(1.0f, a_s);
    for(int i=0;i<8;i++){
        int r=rb+half*8+i;
        if(r<ncnt){
            size_t idx=(size_t)(n0+r)*128+col;
            float o = __fadd_rn(acc[i], Bv[col]);
            X[idx] = __fadd_rn(__fmul_rn(a_s, o), __fmul_rn(om, X[idx]));
        }
    }
}

// ---------- final z GEMM: f32 sequential-k FMA ----------
__global__ void k_zfin(const float* __restrict__ X, const float* __restrict__ W,
                       const float* __restrict__ Bv, float* __restrict__ Z,
                       int n0, int ncnt, int zoff)
{
    __shared__ float sA[16][128];
    int rb=blockIdx.x*16;
    int col=threadIdx.x&63, quad=threadIdx.x>>6;
    for(int i=threadIdx.x;i<2048;i+=256){
        int r=i>>7,c=i&127;
        sA[r][c]=(rb+r<ncnt)?X[(size_t)(n0+rb+r)*128+c]:0.f;
    }
    __syncthreads();
    float acc[4]={0.f,0.f,0.f,0.f};
    for(int k=0;k<128;k++){
        float w=W[(size_t)k*64+col];
#pragma unroll
        for(int i=0;i<4;i++)acc[i]=fmaf(sA[quad*4+i][k], w, acc[i]);
    }
    for(int i=0;i<4;i++){
        int r=rb+quad*4+i;
        if(r<ncnt)Z[(size_t)(zoff+r)*64+col]=__fadd_rn(acc[i], Bv[col]);
    }
}

// ---------- train edge mask (padded index space) ----------
__global__ void k_mask(const int* __restrict__ tr, unsigned* __restrict__ MASK, int E){
    int i = blockIdx.x*256 + threadIdx.x;
    if (i>=E) return;
    unsigned bit = (unsigned)(tr[i]*KROWP + tr[E+i]);
    atomicOr(&MASK[bit>>5], 1u<<(bit&31));
}

// ---------- keys: 64x64 tile, uint4 aligned stores, fused level-0 hist ----------
__global__ void __launch_bounds__(256) k_keys(const float* __restrict__ Z,
        const unsigned* __restrict__ MASK, unsigned* __restrict__ KEYS,
        unsigned* __restrict__ STATE)
{
    __shared__ float sC[64][65];
    __shared__ float sD[64][65];
    __shared__ unsigned shh[256];
    int db = blockIdx.x*64, cb = blockIdx.y*64;
    shh[threadIdx.x] = 0u;
    for (int i=threadIdx.x;i<4096;i+=256){
        int r=i>>6, c=i&63;
        sC[r][c] = (cb+r<N_C) ? Z[(size_t)(cb+r)*64+c] : 0.f;
        sD[r][c] = (db+r<N_D) ? Z[(size_t)(N_C+db+r)*64+c] : 0.f;
    }
    __syncthreads();
    int tx = threadIdx.x & 15, ty = threadIdx.x >> 4;
    int r0 = ty*4, c0 = tx*4;
    float acc[4][4];
#pragma unroll
    for(int i=0;i<4;i++)
#pragma unroll
        for(int j=0;j<4;j++) acc[i][j]=0.f;
    for (int k=0;k<64;k++){
        float a0=sC[r0][k],a1=sC[r0+1][k],a2=sC[r0+2][k],a3=sC[r0+3][k];
        float b0=sD[c0][k],b1=sD[c0+1][k],b2=sD[c0+2][k],b3=sD[c0+3][k];
        acc[0][0]=fmaf(a0,b0,acc[0][0]); acc[0][1]=fmaf(a0,b1,acc[0][1]);
        acc[0][2]=fmaf(a0,b2,acc[0][2]); acc[0][3]=fmaf(a0,b3,acc[0][3]);
        acc[1][0]=fmaf(a1,b0,acc[1][0]); acc[1][1]=fmaf(a1,b1,acc[1][1]);
        acc[1][2]=fmaf(a1,b2,acc[1][2]); acc[1][3]=fmaf(a1,b3,acc[1][3]);
        acc[2][0]=fmaf(a2,b0,acc[2][0]); acc[2][1]=fmaf(a2,b1,acc[2][1]);
        acc[2][2]=fmaf(a2,b2,acc[2][2]); acc[2][3]=fmaf(a2,b3,acc[2][3]);
        acc[3][0]=fmaf(a3,b0,acc[3][0]); acc[3][1]=fmaf(a3,b1,acc[3][1]);
        acc[3][2]=fmaf(a3,b2,acc[3][2]); acc[3][3]=fmaf(a3,b3,acc[3][3]);
    }
    unsigned lastb=0xFFFFFFFFu, rcnt=0;
#pragma unroll
    for (int i=0;i<4;i++){
        int cr = cb + r0 + i;
        int dcb = db + c0;
        bool rok = (cr < N_C);
        unsigned mword = rok ? MASK[((size_t)cr*KROWP + dcb)>>5] : 0u;
        unsigned kk[4];
#pragma unroll
        for (int j=0;j<4;j++){
            int dc = dcb + j;
            unsigned key = 0u;
            if (rok && dc < N_D){
                float p = np_sigmoid_f32(acc[i][j]);
                key = fenc32(p);
                if (mword & (1u << (dc & 31))) key = 0u;
            }
            kk[j] = key;
            unsigned b = key >> 24;
            if (b == lastb) rcnt++;
            else { if (rcnt) atomicAdd(&shh[lastb], rcnt); lastb = b; rcnt = 1; }
        }
        *reinterpret_cast<uint4*>(&KEYS[(size_t)cr*KROWP + dcb]) =
            make_uint4(kk[0],kk[1],kk[2],kk[3]);
    }
    if (rcnt) atomicAdd(&shh[lastb], rcnt);
    __syncthreads();
    unsigned v = shh[threadIdx.x];
    if (v) atomicAdd(&STATE[8+threadIdx.x], v);
}

// ---------- radix select levels 1..3 (RLE bucket aggregation) ----------
__global__ void k_hist(const unsigned* __restrict__ KEYS, unsigned* __restrict__ STATE, int level){
    __shared__ unsigned sh[256];
    for (int i=threadIdx.x;i<256;i+=blockDim.x) sh[i]=0;
    __syncthreads();
    unsigned prefix = STATE[0];
    int shift = 24 - 8*level;
    size_t stride = (size_t)gridDim.x*blockDim.x;
    unsigned lastb = 0xFFFFFFFFu, rcnt = 0;
    for (size_t i = (size_t)blockIdx.x*blockDim.x+threadIdx.x; i < (size_t)NPROBP; i += stride){
        unsigned k = KEYS[i];
        if ((k >> (shift+8)) != prefix) continue;
        unsigned b = (k>>shift)&255u;
        if (b == lastb) rcnt++;
        else { if (rcnt) atomicAdd(&sh[lastb], rcnt); lastb = b; rcnt = 1; }
    }
    if (rcnt) atomicAdd(&sh[lastb], rcnt);
    __syncthreads();
    for (int i=threadIdx.x;i<256;i+=blockDim.x) if (sh[i]) atomicAdd(&STATE[8+i], sh[i]);
}

__global__ void k_hfin(unsigned* STATE){
    if (threadIdx.x==0 && blockIdx.x==0){
        unsigned cnt = STATE[1];
        unsigned prefix = STATE[0];
        int b = 255;
        for (; b>0; --b){
            unsigned c = STATE[8+b];
            if (cnt + c >= (unsigned)KTOP) break;
            cnt += c;
        }
        STATE[0] = (prefix<<8) | (unsigned)b;
        STATE[1] = cnt;
        for (int i=0;i<256;i++) STATE[8+i]=0;
    }
}

// ---------- collect: store (key<<32)|~idx composites for the greater set ----------
__global__ void k_collect(const unsigned* __restrict__ KEYS, unsigned* __restrict__ STATE,
                          unsigned long long* __restrict__ CANDI, unsigned* __restrict__ EQI)
{
    unsigned T = STATE[0];
    size_t stride = (size_t)gridDim.x*blockDim.x;
    for (size_t i=(size_t)blockIdx.x*blockDim.x+threadIdx.x; i<(size_t)NPROBP; i+=stride){
        unsigned k = KEYS[i];
        if (k > T){
            unsigned pos = atomicAdd(&STATE[2], 1u);
            if (pos < 8192u)
                CANDI[pos] = ((unsigned long long)k << 32)
                           | (unsigned long long)(0xFFFFFFFFu - (unsigned)i);
        } else if (k == T){
            unsigned pos = atomicAdd(&STATE[3], 1u);
            if (pos < EQCAP) EQI[pos] = (unsigned)i;
        }
    }
}

// ---------- rank-scatter exact order: multi-block, output-identical to sort ----------
__global__ void __launch_bounds__(256) k_rank(const unsigned long long* __restrict__ CANDI,
        const unsigned* __restrict__ STATE, const unsigned* __restrict__ EQI,
        float* __restrict__ OUT)
{
    __shared__ unsigned long long sc[2048];
    unsigned* se = (unsigned*)sc;
    unsigned G = STATE[2]; if (G > 8192u) G = 8192u;   // radix guarantees G < KTOP
    unsigned nE = STATE[3]; if (nE > 8192u) nE = 8192u;
    unsigned T = STATE[0];
    unsigned need = ((unsigned)KTOP > G) ? ((unsigned)KTOP - G) : 0u;

    int phase = blockIdx.x & 1;
    unsigned i = (blockIdx.x >> 1)*256 + threadIdx.x;   // 0..8191
    if (phase == 0){
        unsigned long long ci = (i < G) ? CANDI[i] : 0ull;
        unsigned rank = 0;
        for (unsigned t0=0; t0<G; t0+=2048u){
            unsigned tl = G - t0; if (tl > 2048u) tl = 2048u;
            __syncthreads();
            for (unsigned k=threadIdx.x; k<tl; k+=256u) sc[k] = CANDI[t0+k];
            __syncthreads();
            if (i < G)
                for (unsigned k=0; k<tl; ++k) rank += (sc[k] > ci) ? 1u : 0u;
        }
        if (i < G){
            unsigned idx = 0xFFFFFFFFu - (unsigned)(ci & 0xFFFFFFFFull);
            unsigned key = (unsigned)(ci >> 32);
            unsigned c = idx/KROWP, d = idx - c*KROWP;
            OUT[rank] = (float)c; OUT[KTOP+rank] = (float)d; OUT[2*KTOP+rank] = fdec32(key);
        }
    } else {
        float pT = fdec32(T);
        unsigned ii = (i < nE) ? EQI[i] : 0xFFFFFFFFu;
        unsigned rank = 0;
        for (unsigned t0=0; t0<nE; t0+=2048u){
            unsigned tl = nE - t0; if (tl > 2048u) tl = 2048u;
            __syncthreads();
            for (unsigned k=threadIdx.x; k<tl; k+=256u) se[k] = EQI[t0+k];
            __syncthreads();
            if (i < nE)
                for (unsigned k=0; k<tl; ++k) rank += (se[k] < ii) ? 1u : 0u;
        }
        if (i < nE && rank < need){
            unsigned c = ii/KROWP, d = ii - c*KROWP;
            unsigned rr = G + rank;
            OUT[rr] = (float)c; OUT[KTOP+rr] = (float)d; OUT[2*KTOP+rr] = pT;
        }
    }
}

// ------------------------------------------------------------------
extern "C" void kernel_launch(void* const* d_in, const int* in_sizes, int n_in,
                              void* d_out, int out_size, void* d_ws, size_t ws_size,
                              hipStream_t stream)
{
    const float* embC = (const float*)d_in[0];
    const float* embD = (const float*)d_in[1];
    const float* embG = (const float*)d_in[2];
    const float* Wkqv = (const float*)d_in[3];
    const float* bkqv = (const float*)d_in[4];
    const float* Wout = (const float*)d_in[5];
    const float* bout = (const float*)d_in[6];
    const float* skipv= (const float*)d_in[7];
    const float* arel = (const float*)d_in[8];
    const float* mrel = (const float*)d_in[9];
    const float* prel = (const float*)d_in[10];
    const float* Wfin = (const float*)d_in[11];
    const float* bfin = (const float*)d_in[12];
    const int* ei[5] = {(const int*)d_in[13],(const int*)d_in[14],(const int*)d_in[15],
                        (const int*)d_in[16],(const int*)d_in[17]};
    const int* tri  = (const int*)d_in[18];
    int trE = in_sizes[18]/2;

    static const int NODE_OFF[3] = {0, N_C, N_C + N_D};
    static const int NODE_CNT[3] = {N_C, N_D, N_G};
    static const int EM_ST[5] = {0,1,0,2,2};
    static const int EM_DT[5] = {1,0,2,0,2};
    static const int EM_E[5]  = {80000,80000,250000,250000,400000};
    static const int EM_OFF[5]= {0,80000,160000,410000,660000};
    static const int DOFF[5] = {0,3000,18000,58000,73000};
    static const int OFO[5]  = {0,3001,18002,58003,73004};

    // ---- workspace layout; PEAK = 249,192,032 bytes ----
    char* ws = (char*)d_ws;
    float* X  = (float*)(ws + 0);                        // 29,696,000
    float* KQ = (float*)(ws + 29696000);                 // 59,392,000
    float* V  = (float*)(ws + 89088000);                 // 29,696,000
    float* ALPHA = (float*)(ws + 118784000);             // 16,960,000 (becomes W)
    unsigned* NMAX = (unsigned*)(ws + 135744000);        // 928,000
    unsigned long long* NSUM = (unsigned long long*)(ws + 136672000); // 1,856,000
    unsigned long long* AGG = (unsigned long long*)(ws + 139456000);  // 59,392,000
    float* VE = (float*)(ws + 198848000);                // 20,480,000
    unsigned* OFFS = (unsigned*)(ws + 219328000);        // 452,032
    unsigned* CURS = (unsigned*)(ws + 219780032);        // 452,000
    unsigned* CSRS = (unsigned*)(ws + 220232032);        // 4,240,000
    unsigned* CSRE = (unsigned*)(ws + 224472032);        // 4,240,000 .. 228,712,032
    float* KE = (float*)(ws + 228712032);                // 20,480,000 .. 249,192,032
    // decode-phase overlays (tenants dead by first use):
    unsigned* KEYS = (unsigned*)(ws + 0);                // 184,811,520
    float* Z = (float*)(ws + 198848000);                 // 4,608,000 (ex-VE)
    unsigned* MASK = (unsigned*)(ws + 203456000);        // 5,760,000
    unsigned* STATE= (unsigned*)(ws + 209216000);        // 8,192
    unsigned long long* CANDI = (unsigned long long*)(ws + 209224192); // 65,536
    unsigned* EQI  = (unsigned*)(ws + 209289728);        // 4,194,304 .. 213,484,032

    hipMemcpyAsync(X,                          embC, (size_t)N_C*HID*4, hipMemcpyDeviceToDevice, stream);
    hipMemcpyAsync(X + (size_t)N_C*HID,        embD, (size_t)N_D*HID*4, hipMemcpyDeviceToDevice, stream);
    hipMemcpyAsync(X + (size_t)(N_C+N_D)*HID,  embG, (size_t)N_G*HID*4, hipMemcpyDeviceToDevice, stream);

    // ---- build CSR once; reused by both layers ----
    hipMemsetAsync(CURS, 0, 113000*4, stream);
    for (int e=0;e<5;e++)
        k_count<<<(EM_E[e]+255)/256, 256, 0, stream>>>(ei[e]+EM_E[e], CURS + DOFF[e], EM_E[e]);
    for (int e=0;e<5;e++)
        k_scan<<<1, 256, 0, stream>>>(CURS + DOFF[e], OFFS + OFO[e], NODE_CNT[EM_DT[e]]);
    hipMemsetAsync(CURS, 0, 113000*4, stream);
    for (int e=0;e<5;e++)
        k_fill<<<(EM_E[e]+255)/256, 256, 0, stream>>>(ei[e], ei[e]+EM_E[e],
            OFFS + OFO[e], CURS + DOFF[e], CSRS, CSRE, EM_E[e], EM_OFF[e]);

    for (int l=0; l<2; ++l){
        k_init_nmax<<<(NTOT*HEADS+255)/256, 256, 0, stream>>>(NMAX);
        hipMemsetAsync(NSUM, 0, (size_t)NTOT*HEADS*8, stream);
        hipMemsetAsync(AGG,  0, (size_t)NTOT*HID*8,  stream);
        for (int t=0;t<3;t++){
            k_kqv<<<dim3((NODE_CNT[t]+15)/16, 3), 256, 0, stream>>>(
                X, Wkqv + (size_t)(l*3+t)*128*384, bkqv + (size_t)(l*3+t)*384,
                KQ, V, NODE_OFF[t], NODE_CNT[t]);
        }
        for (int e=0;e<5;e++){
            int nsrc = NODE_CNT[EM_ST[e]];
            k_rel<<<(nsrc+1)/2, 256, 0, stream>>>(
                KQ, 256, 0, arel + (size_t)(l*5+e)*HEADS*DH*DH, KE,
                NODE_OFF[EM_ST[e]], nsrc);
            int ngrp = (EM_E[e] + EPB - 1) / EPB;      // 128-lane groups
            k_alpha4<<<(ngrp+1)/2, 256, 0, stream>>>(
                KQ, KE, ei[e], ei[e]+EM_E[e],
                prel + (size_t)(l*5+e)*HEADS,
                ALPHA, NMAX, EM_E[e], EM_OFF[e], NODE_OFF[EM_DT[e]]);
        }
        for (int e=0;e<5;e++){
            int tot = EM_E[e]*HEADS;
            k_expsum<<<(tot+255)/256, 256, 0, stream>>>(
                ALPHA, ei[e]+EM_E[e], NMAX, NSUM, EM_E[e], EM_OFF[e], NODE_OFF[EM_DT[e]]);
        }
        for (int e=0;e<5;e++){
            int tot = EM_E[e]*HEADS;
            k_wgt<<<(tot+255)/256, 256, 0, stream>>>(
                ALPHA, ei[e]+EM_E[e], NMAX, NSUM, EM_E[e], EM_OFF[e], NODE_OFF[EM_DT[e]]);
        }
        for (int e=0;e<5;e++){
            int nsrc = NODE_CNT[EM_ST[e]];
            int ndst = NODE_CNT[EM_DT[e]];
            k_rel<<<(nsrc+1)/2, 256, 0, stream>>>(
                V, 128, 0, mrel + (size_t)(l*5+e)*HEADS*DH*DH, VE,
                NODE_OFF[EM_ST[e]], nsrc);
            k_agg2<<<(ndst+DPB-1)/DPB, 128, 0, stream>>>(
                VE, CSRS, CSRE, OFFS + OFO[e], ALPHA, AGG,
                EM_OFF[e], NODE_OFF[EM_DT[e]], EM_OFF[e], ndst);
        }
        for (int t=0;t<3;t++){
            k_outl<<<(NODE_CNT[t]+15)/16, 256, 0, stream>>>(
                AGG, Wout + (size_t)(l*3+t)*128*128, bout + (size_t)(l*3+t)*128,
                X, skipv + (l*3+t), NODE_OFF[t], NODE_CNT[t]);
        }
    }

    k_zfin<<<(N_C+15)/16, 256, 0, stream>>>(X, Wfin + 0,      bfin + 0,  Z, 0,   N_C, 0);
    k_zfin<<<(N_D+15)/16, 256, 0, stream>>>(X, Wfin + 128*64, bfin + 64, Z, N_C, N_D, N_C);

    hipMemsetAsync(MASK, 0, 5760000, stream);
    hipMemsetAsync(STATE, 0, 8192, stream);
    k_mask<<<(trE+255)/256, 256, 0, stream>>>(tri, MASK, trE);
    k_keys<<<dim3(48, 235), 256, 0, stream>>>(Z, MASK, KEYS, STATE);
    k_hfin<<<1, 64, 0, stream>>>(STATE);
    for (int lev=1; lev<4; ++lev){
        k_hist<<<2048, 256, 0, stream>>>(KEYS, STATE, lev);
        k_hfin<<<1, 64, 0, stream>>>(STATE);
    }
    k_collect<<<2048, 256, 0, stream>>>(KEYS, STATE, CANDI, EQI);
    k_rank<<<64, 256, 0, stream>>>(CANDI, STATE, EQI, (float*)d_out);
}